// Round 1
// baseline (892.187 us; speedup 1.0000x reference)
//
#include <hip/hip_runtime.h>
#include <hip/hip_bf16.h>

// Problem constants (fixed by the reference).
#define NNODES 10000
#define NEDGES 160000
#define FIN    2208
#define HDIM   512
#define NCLS   2

// ---------------- graph preprocessing ----------------

__global__ void k_init(int* cnt, int* row_cnt, int n) {
    int i = blockIdx.x * blockDim.x + threadIdx.x;
    if (i < n) { cnt[i] = 0; row_cnt[i] = 0; }
}

__global__ void k_hist(const int* __restrict__ ei, int* __restrict__ cnt, int e) {
    int i = blockIdx.x * blockDim.x + threadIdx.x;
    if (i < e) {
        int dst = ei[NEDGES + i];
        atomicAdd(&cnt[dst], 1);
    }
}

// single-block inclusive scan -> row_ptr (exclusive form: row_ptr[0]=0, row_ptr[i+1]=incl[i])
__global__ void k_scan(const int* __restrict__ cnt, int* __restrict__ row_ptr, int n) {
    __shared__ int sdata[1024];
    __shared__ int carry;
    int tid = threadIdx.x;
    if (tid == 0) carry = 0;
    __syncthreads();
    for (int base = 0; base < n; base += 1024) {
        int i = base + tid;
        int v = (i < n) ? cnt[i] : 0;
        sdata[tid] = v;
        __syncthreads();
        for (int off = 1; off < 1024; off <<= 1) {
            int t = (tid >= off) ? sdata[tid - off] : 0;
            __syncthreads();
            sdata[tid] += t;
            __syncthreads();
        }
        int incl = sdata[tid] + carry;
        if (i < n) row_ptr[i + 1] = incl;
        __syncthreads();
        if (tid == 0) carry = carry + sdata[1023];
        __syncthreads();
    }
    if (tid == 0) row_ptr[0] = 0;
}

__global__ void k_dinv(const int* __restrict__ cnt, float* __restrict__ dinv, int n) {
    int i = blockIdx.x * blockDim.x + threadIdx.x;
    if (i < n) {
        float deg = (float)cnt[i] + 1.0f;   // +1 self-loop
        dinv[i] = rsqrtf(deg);
    }
}

__global__ void k_fill(const int* __restrict__ ei, const int* __restrict__ row_ptr,
                       int* __restrict__ row_cnt, int* __restrict__ col_src, int e) {
    int i = blockIdx.x * blockDim.x + threadIdx.x;
    if (i < e) {
        int src = ei[i];
        int dst = ei[NEDGES + i];
        int pos = row_ptr[dst] + atomicAdd(&row_cnt[dst], 1);
        col_src[pos] = src;
    }
}

// ---------------- fp32 tiled GEMM: C[M,N] = A[M,K] @ B[K,N] ----------------
// 128x128 block tile, 8x8 micro-tile (split 4+4 with 64 offset), K-tile 16.

#define TILE_K 16
#define LDSP 132   // row pitch in floats; 132*4=528 B, multiple of 16 -> aligned float4

__global__ __launch_bounds__(256, 2) void k_gemm(const float* __restrict__ A,
                                                 const float* __restrict__ B,
                                                 float* __restrict__ C,
                                                 int M, int N, int K) {
    __shared__ float As[TILE_K][LDSP];
    __shared__ float Bs[TILE_K][LDSP];
    const int tid = threadIdx.x;
    const int tx = tid & 15;   // 0..15 col group
    const int ty = tid >> 4;   // 0..15 row group
    const int bm = blockIdx.x * 128;
    const int bn = blockIdx.y * 128;

    float acc[8][8] = {};

    for (int k0 = 0; k0 < K; k0 += TILE_K) {
        // stage A tile (128 rows x 16 k), transposed into As[k][m]
        #pragma unroll
        for (int i = 0; i < 2; ++i) {
            int idx = tid + i * 256;
            int r = idx >> 2;       // 0..127
            int q = idx & 3;        // float4 within the 16-wide k segment
            int row = bm + r;
            if (row >= M) row = M - 1;           // clamp: garbage rows discarded at store
            const float4 v = *(const float4*)(A + (size_t)row * K + k0 + q * 4);
            As[q * 4 + 0][r] = v.x;
            As[q * 4 + 1][r] = v.y;
            As[q * 4 + 2][r] = v.z;
            As[q * 4 + 3][r] = v.w;
        }
        // stage B tile (16 k x 128 n)
        #pragma unroll
        for (int i = 0; i < 2; ++i) {
            int idx = tid + i * 256;
            int kr = idx >> 5;      // 0..15
            int q  = idx & 31;      // float4 col group
            const float4 v = *(const float4*)(B + (size_t)(k0 + kr) * N + bn + q * 4);
            *(float4*)&Bs[kr][q * 4] = v;
        }
        __syncthreads();

        #pragma unroll
        for (int k = 0; k < TILE_K; ++k) {
            float4 a0 = *(const float4*)&As[k][ty * 4];
            float4 a1 = *(const float4*)&As[k][64 + ty * 4];
            float4 b0 = *(const float4*)&Bs[k][tx * 4];
            float4 b1 = *(const float4*)&Bs[k][64 + tx * 4];
            float av[8] = {a0.x, a0.y, a0.z, a0.w, a1.x, a1.y, a1.z, a1.w};
            float bv[8] = {b0.x, b0.y, b0.z, b0.w, b1.x, b1.y, b1.z, b1.w};
            #pragma unroll
            for (int i = 0; i < 8; ++i)
                #pragma unroll
                for (int j = 0; j < 8; ++j)
                    acc[i][j] += av[i] * bv[j];
        }
        __syncthreads();
    }

    // write back: rows {ty*4+0..3, 64+ty*4+0..3}, cols {tx*4+0..3, 64+tx*4+0..3}
    #pragma unroll
    for (int i = 0; i < 8; ++i) {
        int r = bm + ((i < 4) ? (ty * 4 + i) : (64 + ty * 4 + (i - 4)));
        if (r < M) {
            float4 o0 = make_float4(acc[i][0], acc[i][1], acc[i][2], acc[i][3]);
            float4 o1 = make_float4(acc[i][4], acc[i][5], acc[i][6], acc[i][7]);
            *(float4*)(C + (size_t)r * N + bn + tx * 4) = o0;
            *(float4*)(C + (size_t)r * N + bn + 64 + tx * 4) = o1;
        }
    }
}

// ---------------- aggregation (512 features): one wave per node ----------------
// H[d] = relu( dinv[d]^2 * Y[d] + sum_{s in N(d)} dinv[d]*dinv[s]*Y[s] + b )

__global__ void k_agg(const float* __restrict__ Y, const float* __restrict__ dinv,
                      const int* __restrict__ row_ptr, const int* __restrict__ col_src,
                      const float* __restrict__ bias, float* __restrict__ H,
                      int n, int do_relu) {
    int w = (blockIdx.x * blockDim.x + threadIdx.x) >> 6;
    int lane = threadIdx.x & 63;
    if (w >= n) return;
    float di = dinv[w];
    const float4* yr = (const float4*)(Y + (size_t)w * HDIM);
    float4 a0 = yr[lane];
    float4 a1 = yr[lane + 64];
    float sw = di * di;
    a0.x *= sw; a0.y *= sw; a0.z *= sw; a0.w *= sw;
    a1.x *= sw; a1.y *= sw; a1.z *= sw; a1.w *= sw;
    int e0 = row_ptr[w], e1 = row_ptr[w + 1];
    for (int e = e0; e < e1; ++e) {
        int s = col_src[e];
        float wgt = di * dinv[s];
        const float4* sr = (const float4*)(Y + (size_t)s * HDIM);
        float4 v0 = sr[lane];
        float4 v1 = sr[lane + 64];
        a0.x += wgt * v0.x; a0.y += wgt * v0.y; a0.z += wgt * v0.z; a0.w += wgt * v0.w;
        a1.x += wgt * v1.x; a1.y += wgt * v1.y; a1.z += wgt * v1.z; a1.w += wgt * v1.w;
    }
    const float4* bb = (const float4*)bias;
    float4 b0 = bb[lane], b1 = bb[lane + 64];
    a0.x += b0.x; a0.y += b0.y; a0.z += b0.z; a0.w += b0.w;
    a1.x += b1.x; a1.y += b1.y; a1.z += b1.z; a1.w += b1.w;
    if (do_relu) {
        a0.x = fmaxf(a0.x, 0.f); a0.y = fmaxf(a0.y, 0.f);
        a0.z = fmaxf(a0.z, 0.f); a0.w = fmaxf(a0.w, 0.f);
        a1.x = fmaxf(a1.x, 0.f); a1.y = fmaxf(a1.y, 0.f);
        a1.z = fmaxf(a1.z, 0.f); a1.w = fmaxf(a1.w, 0.f);
    }
    float4* hr = (float4*)(H + (size_t)w * HDIM);
    hr[lane] = a0;
    hr[lane + 64] = a1;
}

// ---------------- layer-4 GEMM (K=512, N=2): one wave per row ----------------

__global__ void k_gemm4(const float* __restrict__ H, const float* __restrict__ W4,
                        float* __restrict__ Y4, int n) {
    int w = (blockIdx.x * blockDim.x + threadIdx.x) >> 6;
    int lane = threadIdx.x & 63;
    if (w >= n) return;
    const float4* hr = (const float4*)(H + (size_t)w * HDIM);
    const float4* wf = (const float4*)W4;   // W4 flat [512*2], row-major [k][c]
    float4 h0 = hr[lane];        // k = 4*lane .. +3
    float4 h1 = hr[lane + 64];   // k = 4*(lane+64) .. +3
    float4 wa = wf[lane * 2];
    float4 wb = wf[lane * 2 + 1];
    float4 wc = wf[(lane + 64) * 2];
    float4 wd = wf[(lane + 64) * 2 + 1];
    float acc0 = h0.x * wa.x + h0.y * wa.z + h0.z * wb.x + h0.w * wb.z
               + h1.x * wc.x + h1.y * wc.z + h1.z * wd.x + h1.w * wd.z;
    float acc1 = h0.x * wa.y + h0.y * wa.w + h0.z * wb.y + h0.w * wb.w
               + h1.x * wc.y + h1.y * wc.w + h1.z * wd.y + h1.w * wd.w;
    #pragma unroll
    for (int off = 32; off > 0; off >>= 1) {
        acc0 += __shfl_down(acc0, off);
        acc1 += __shfl_down(acc1, off);
    }
    if (lane == 0) {
        Y4[2 * w] = acc0;
        Y4[2 * w + 1] = acc1;
    }
}

// ---------------- layer-4 aggregation + bias + log_softmax ----------------

__global__ void k_final(const float* __restrict__ Y4, const float* __restrict__ dinv,
                        const int* __restrict__ row_ptr, const int* __restrict__ col_src,
                        const float* __restrict__ b4, float* __restrict__ out, int n) {
    int i = blockIdx.x * blockDim.x + threadIdx.x;
    if (i >= n) return;
    float di = dinv[i];
    float sw = di * di;
    float z0 = sw * Y4[2 * i];
    float z1 = sw * Y4[2 * i + 1];
    int e0 = row_ptr[i], e1 = row_ptr[i + 1];
    for (int e = e0; e < e1; ++e) {
        int s = col_src[e];
        float wgt = di * dinv[s];
        z0 += wgt * Y4[2 * s];
        z1 += wgt * Y4[2 * s + 1];
    }
    z0 += b4[0];
    z1 += b4[1];
    float m = fmaxf(z0, z1);
    float l = m + logf(expf(z0 - m) + expf(z1 - m));
    out[2 * i] = z0 - l;
    out[2 * i + 1] = z1 - l;
}

// ---------------- launch ----------------

extern "C" void kernel_launch(void* const* d_in, const int* in_sizes, int n_in,
                              void* d_out, int out_size, void* d_ws, size_t ws_size,
                              hipStream_t stream) {
    const float* x  = (const float*)d_in[0];
    const int*   ei = (const int*)d_in[1];
    // d_in[2] = batch (unused)
    const float* W1 = (const float*)d_in[3];
    const float* b1 = (const float*)d_in[4];
    const float* W2 = (const float*)d_in[5];
    const float* b2 = (const float*)d_in[6];
    const float* W3 = (const float*)d_in[7];
    const float* b3 = (const float*)d_in[8];
    const float* W4 = (const float*)d_in[9];
    const float* b4 = (const float*)d_in[10];
    float* out = (float*)d_out;

    char* ws = (char*)d_ws;
    // offsets (bytes), all 256-aligned
    float* dinv    = (float*)(ws + 0);          // N floats
    int*   cnt     = (int*)  (ws + 40960);      // N ints
    int*   row_cnt = (int*)  (ws + 81920);      // N ints
    int*   row_ptr = (int*)  (ws + 122880);     // N+1 ints
    int*   col_src = (int*)  (ws + 163840);     // E ints (640000 B)
    float* Y4      = (float*)(ws + 803840);     // N*2 floats (80000 B)
    float* bufA    = (float*)(ws + 884224);     // N*512 floats (20.48 MB)
    float* bufB    = (float*)(ws + 884224 + 20480000);

    // graph preprocessing: degrees, CSR by destination
    k_init<<<40, 256, 0, stream>>>(cnt, row_cnt, NNODES);
    k_hist<<<625, 256, 0, stream>>>(ei, cnt, NEDGES);
    k_scan<<<1, 1024, 0, stream>>>(cnt, row_ptr, NNODES);
    k_dinv<<<40, 256, 0, stream>>>(cnt, dinv, NNODES);
    k_fill<<<625, 256, 0, stream>>>(ei, row_ptr, row_cnt, col_src, NEDGES);

    dim3 ggrid(79, 4);  // ceil(10000/128) x 512/128

    // layer 1
    k_gemm<<<ggrid, 256, 0, stream>>>(x, W1, bufA, NNODES, HDIM, FIN);
    k_agg<<<2500, 256, 0, stream>>>(bufA, dinv, row_ptr, col_src, b1, bufB, NNODES, 1);
    // layer 2
    k_gemm<<<ggrid, 256, 0, stream>>>(bufB, W2, bufA, NNODES, HDIM, HDIM);
    k_agg<<<2500, 256, 0, stream>>>(bufA, dinv, row_ptr, col_src, b2, bufB, NNODES, 1);
    // layer 3
    k_gemm<<<ggrid, 256, 0, stream>>>(bufB, W3, bufA, NNODES, HDIM, HDIM);
    k_agg<<<2500, 256, 0, stream>>>(bufA, dinv, row_ptr, col_src, b3, bufB, NNODES, 1);
    // layer 4 + log_softmax
    k_gemm4<<<2500, 256, 0, stream>>>(bufB, W4, Y4, NNODES);
    k_final<<<40, 256, 0, stream>>>(Y4, dinv, row_ptr, col_src, b4, out, NNODES);
}

// Round 2
// 471.054 us; speedup vs baseline: 1.8940x; 1.8940x over previous
//
#include <hip/hip_runtime.h>
#include <hip/hip_bf16.h>

// Problem constants (fixed by the reference).
#define NNODES 10000
#define NEDGES 160000
#define FIN    2208
#define HDIM   512
#define NCLS   2

#define MPAD   10112     // 79 * 128
#define K1PAD  2240      // 2208 padded to multiple of 64

typedef __bf16 bf16x8 __attribute__((ext_vector_type(8)));
typedef float  f32x4  __attribute__((ext_vector_type(4)));

__device__ inline unsigned short f2bf(float f) {
    union { float f; unsigned int u; } v; v.f = f;
    return (unsigned short)((v.u + 0x7FFFu + ((v.u >> 16) & 1u)) >> 16);
}
__device__ inline float bf2f(unsigned short u) {
    union { unsigned int i; float f; } v; v.i = ((unsigned int)u) << 16; return v.f;
}

// ---------------- graph preprocessing ----------------

__global__ void k_init(int* cnt, int* row_cnt, int n) {
    int i = blockIdx.x * blockDim.x + threadIdx.x;
    if (i < n) { cnt[i] = 0; row_cnt[i] = 0; }
}

__global__ void k_hist(const int* __restrict__ ei, int* __restrict__ cnt, int e) {
    int i = blockIdx.x * blockDim.x + threadIdx.x;
    if (i < e) atomicAdd(&cnt[ei[NEDGES + i]], 1);
}

__global__ void k_scan(const int* __restrict__ cnt, int* __restrict__ row_ptr, int n) {
    __shared__ int sdata[1024];
    __shared__ int carry;
    int tid = threadIdx.x;
    if (tid == 0) carry = 0;
    __syncthreads();
    for (int base = 0; base < n; base += 1024) {
        int i = base + tid;
        int v = (i < n) ? cnt[i] : 0;
        sdata[tid] = v;
        __syncthreads();
        for (int off = 1; off < 1024; off <<= 1) {
            int t = (tid >= off) ? sdata[tid - off] : 0;
            __syncthreads();
            sdata[tid] += t;
            __syncthreads();
        }
        int incl = sdata[tid] + carry;
        if (i < n) row_ptr[i + 1] = incl;
        __syncthreads();
        if (tid == 0) carry = carry + sdata[1023];
        __syncthreads();
    }
    if (tid == 0) row_ptr[0] = 0;
}

__global__ void k_dinv(const int* __restrict__ cnt, float* __restrict__ dinv, int n) {
    int i = blockIdx.x * blockDim.x + threadIdx.x;
    if (i < n) dinv[i] = rsqrtf((float)cnt[i] + 1.0f);
}

__global__ void k_fill(const int* __restrict__ ei, const int* __restrict__ row_ptr,
                       int* __restrict__ row_cnt, int* __restrict__ col_src, int e) {
    int i = blockIdx.x * blockDim.x + threadIdx.x;
    if (i < e) {
        int src = ei[i];
        int dst = ei[NEDGES + i];
        int pos = row_ptr[dst] + atomicAdd(&row_cnt[dst], 1);
        col_src[pos] = src;
    }
}

// ---------------- converters ----------------

// x fp32 [10000][2208] -> xb bf16 [MPAD][K1PAD], zero-padded
__global__ void k_cvt_x(const float* __restrict__ x, unsigned short* __restrict__ xb) {
    int col = blockIdx.x * 256 + threadIdx.x;
    int row = blockIdx.y;
    if (col >= K1PAD) return;
    float v = (row < NNODES && col < FIN) ? x[(size_t)row * FIN + col] : 0.0f;
    xb[(size_t)row * K1PAD + col] = f2bf(v);
}

// W fp32 [K][512] -> Wt bf16 [512][Kp], zero-padded in k
__global__ void k_cvt_wt(const float* __restrict__ W, unsigned short* __restrict__ Wt,
                         int Kreal, int Kp) {
    int k = blockIdx.x * 256 + threadIdx.x;
    int n = blockIdx.y;
    if (k >= Kp) return;
    float v = (k < Kreal) ? W[(size_t)k * HDIM + n] : 0.0f;
    Wt[(size_t)n * Kp + k] = f2bf(v);
}

// ---------------- bf16 MFMA GEMM: C[M,512] = A[M,K] @ Bt[512,K]^T ----------------
// 128x128 tile, BK=64, 4 waves in 2x2, each wave 64x64 via 4x4 MFMA 16x16x32.
// LDS: row-major [128][64] bf16 with XOR swizzle on 16B chunks -> conflict-free
// b128 fragment reads; staged via global_load_lds width 16.

#define BKK 64

__global__ __launch_bounds__(256) void k_gemm_bf16(
    const unsigned short* __restrict__ A,   // [Mpad][K] bf16
    const unsigned short* __restrict__ Bt,  // [512][K] bf16 (W transposed)
    float* __restrict__ C,                  // [Mpad][512] fp32
    int M, int K) {
    __shared__ char As[128 * BKK * 2] __attribute__((aligned(16)));  // 16 KB
    __shared__ char Bs[128 * BKK * 2] __attribute__((aligned(16)));  // 16 KB
    const int tid  = threadIdx.x;
    const int lane = tid & 63;
    const int w    = tid >> 6;
    const int wm   = w & 1, wn = w >> 1;
    const int quad = lane >> 4, lq = lane & 15;
    const int bm = blockIdx.x * 128, bn = blockIdx.y * 128;

    f32x4 acc[4][4] = {};

    for (int k0 = 0; k0 < K; k0 += BKK) {
        // stage A and B tiles: 1024 chunks of 16B each, 4 issues/thread each
        #pragma unroll
        for (int i = 0; i < 4; ++i) {
            int c  = i * 256 + tid;
            int r  = c >> 3;
            int g  = (c & 7) ^ (r & 7);     // XOR swizzle: LDS chunk c holds global chunk g
            const char* gpA = (const char*)A  + ((size_t)(bm + r) * K + k0) * 2 + (g << 4);
            const char* gpB = (const char*)Bt + ((size_t)(bn + r) * K + k0) * 2 + (g << 4);
            __builtin_amdgcn_global_load_lds(
                (const __attribute__((address_space(1))) void*)gpA,
                (__attribute__((address_space(3))) void*)(As + c * 16), 16, 0, 0);
            __builtin_amdgcn_global_load_lds(
                (const __attribute__((address_space(1))) void*)gpB,
                (__attribute__((address_space(3))) void*)(Bs + c * 16), 16, 0, 0);
        }
        __syncthreads();

        #pragma unroll
        for (int s = 0; s < 2; ++s) {
            bf16x8 af[4], bfr[4];
            #pragma unroll
            for (int i = 0; i < 4; ++i) {
                int r = wm * 64 + i * 16 + lq;
                int g = s * 4 + quad;
                af[i]  = *(const bf16x8*)(As + r * 128 + (((g) ^ (r & 7)) << 4));
                int n = wn * 64 + i * 16 + lq;
                bfr[i] = *(const bf16x8*)(Bs + n * 128 + (((g) ^ (n & 7)) << 4));
            }
            #pragma unroll
            for (int i = 0; i < 4; ++i)
                #pragma unroll
                for (int j = 0; j < 4; ++j)
                    acc[i][j] = __builtin_amdgcn_mfma_f32_16x16x32_bf16(
                        af[i], bfr[j], acc[i][j], 0, 0, 0);
        }
        __syncthreads();
    }

    // C/D layout: col = lane&15, row = quad*4 + reg  (m89-verified)
    #pragma unroll
    for (int i = 0; i < 4; ++i) {
        #pragma unroll
        for (int p = 0; p < 4; ++p) {
            int r = bm + wm * 64 + i * 16 + quad * 4 + p;
            if (r < M) {
                #pragma unroll
                for (int j = 0; j < 4; ++j) {
                    int col = bn + wn * 64 + j * 16 + lq;
                    C[(size_t)r * HDIM + col] = acc[i][j][p];
                }
            }
        }
    }
}

// ---------------- aggregation: fp32 in, fp32 accumulate, bf16 out ----------------
// Hb[d] = bf16( relu( dinv[d]^2*Y[d] + sum_s dinv[d]dinv[s]*Y[s] + b ) )
// Waves w >= NNODES zero-fill padding rows (GEMM stages them).

__global__ void k_agg(const float* __restrict__ Y, const float* __restrict__ dinv,
                      const int* __restrict__ row_ptr, const int* __restrict__ col_src,
                      const float* __restrict__ bias, unsigned short* __restrict__ Hb,
                      int do_relu) {
    int w = (blockIdx.x * blockDim.x + threadIdx.x) >> 6;
    int lane = threadIdx.x & 63;
    if (w >= MPAD) return;
    unsigned short* hr = Hb + (size_t)w * HDIM;
    if (w >= NNODES) {
        ushort4 z = {0, 0, 0, 0};
        *(ushort4*)(hr + lane * 4) = z;
        *(ushort4*)(hr + 256 + lane * 4) = z;
        return;
    }
    float di = dinv[w];
    const float4* yr = (const float4*)(Y + (size_t)w * HDIM);
    float4 a0 = yr[lane];
    float4 a1 = yr[lane + 64];
    float sw = di * di;
    a0.x *= sw; a0.y *= sw; a0.z *= sw; a0.w *= sw;
    a1.x *= sw; a1.y *= sw; a1.z *= sw; a1.w *= sw;
    int e0 = row_ptr[w], e1 = row_ptr[w + 1];
    for (int e = e0; e < e1; ++e) {
        int s = col_src[e];
        float wgt = di * dinv[s];
        const float4* sr = (const float4*)(Y + (size_t)s * HDIM);
        float4 v0 = sr[lane];
        float4 v1 = sr[lane + 64];
        a0.x += wgt * v0.x; a0.y += wgt * v0.y; a0.z += wgt * v0.z; a0.w += wgt * v0.w;
        a1.x += wgt * v1.x; a1.y += wgt * v1.y; a1.z += wgt * v1.z; a1.w += wgt * v1.w;
    }
    const float4* bb = (const float4*)bias;
    float4 b0 = bb[lane], b1 = bb[lane + 64];
    a0.x += b0.x; a0.y += b0.y; a0.z += b0.z; a0.w += b0.w;
    a1.x += b1.x; a1.y += b1.y; a1.z += b1.z; a1.w += b1.w;
    if (do_relu) {
        a0.x = fmaxf(a0.x, 0.f); a0.y = fmaxf(a0.y, 0.f);
        a0.z = fmaxf(a0.z, 0.f); a0.w = fmaxf(a0.w, 0.f);
        a1.x = fmaxf(a1.x, 0.f); a1.y = fmaxf(a1.y, 0.f);
        a1.z = fmaxf(a1.z, 0.f); a1.w = fmaxf(a1.w, 0.f);
    }
    ushort4 o0 = {f2bf(a0.x), f2bf(a0.y), f2bf(a0.z), f2bf(a0.w)};
    ushort4 o1 = {f2bf(a1.x), f2bf(a1.y), f2bf(a1.z), f2bf(a1.w)};
    *(ushort4*)(hr + lane * 4) = o0;
    *(ushort4*)(hr + 256 + lane * 4) = o1;
}

// ---------------- layer-4 GEMM (bf16 H, K=512, N=2): one wave per row ----------------

__global__ void k_gemm4(const unsigned short* __restrict__ H, const float* __restrict__ W4,
                        float* __restrict__ Y4, int n) {
    int w = (blockIdx.x * blockDim.x + threadIdx.x) >> 6;
    int lane = threadIdx.x & 63;
    if (w >= n) return;
    const unsigned short* hr = H + (size_t)w * HDIM + lane * 8;
    ushort4 hA = *(const ushort4*)hr;
    ushort4 hB = *(const ushort4*)(hr + 4);
    float hv[8] = {bf2f(hA.x), bf2f(hA.y), bf2f(hA.z), bf2f(hA.w),
                   bf2f(hB.x), bf2f(hB.y), bf2f(hB.z), bf2f(hB.w)};
    const float4* wf = (const float4*)W4;  // [k][c] flat
    float4 w0 = wf[lane * 4 + 0];
    float4 w1 = wf[lane * 4 + 1];
    float4 w2 = wf[lane * 4 + 2];
    float4 w3 = wf[lane * 4 + 3];
    float acc0 = hv[0]*w0.x + hv[1]*w0.z + hv[2]*w1.x + hv[3]*w1.z
               + hv[4]*w2.x + hv[5]*w2.z + hv[6]*w3.x + hv[7]*w3.z;
    float acc1 = hv[0]*w0.y + hv[1]*w0.w + hv[2]*w1.y + hv[3]*w1.w
               + hv[4]*w2.y + hv[5]*w2.w + hv[6]*w3.y + hv[7]*w3.w;
    #pragma unroll
    for (int off = 32; off > 0; off >>= 1) {
        acc0 += __shfl_down(acc0, off);
        acc1 += __shfl_down(acc1, off);
    }
    if (lane == 0) {
        Y4[2 * w] = acc0;
        Y4[2 * w + 1] = acc1;
    }
}

// ---------------- layer-4 aggregation + bias + log_softmax ----------------

__global__ void k_final(const float* __restrict__ Y4, const float* __restrict__ dinv,
                        const int* __restrict__ row_ptr, const int* __restrict__ col_src,
                        const float* __restrict__ b4, float* __restrict__ out, int n) {
    int i = blockIdx.x * blockDim.x + threadIdx.x;
    if (i >= n) return;
    float di = dinv[i];
    float sw = di * di;
    float z0 = sw * Y4[2 * i];
    float z1 = sw * Y4[2 * i + 1];
    int e0 = row_ptr[i], e1 = row_ptr[i + 1];
    for (int e = e0; e < e1; ++e) {
        int s = col_src[e];
        float wgt = di * dinv[s];
        z0 += wgt * Y4[2 * s];
        z1 += wgt * Y4[2 * s + 1];
    }
    z0 += b4[0];
    z1 += b4[1];
    float m = fmaxf(z0, z1);
    float l = m + logf(expf(z0 - m) + expf(z1 - m));
    out[2 * i] = z0 - l;
    out[2 * i + 1] = z1 - l;
}

// ---------------- launch ----------------

extern "C" void kernel_launch(void* const* d_in, const int* in_sizes, int n_in,
                              void* d_out, int out_size, void* d_ws, size_t ws_size,
                              hipStream_t stream) {
    const float* x  = (const float*)d_in[0];
    const int*   ei = (const int*)d_in[1];
    const float* W1 = (const float*)d_in[3];
    const float* b1 = (const float*)d_in[4];
    const float* W2 = (const float*)d_in[5];
    const float* b2 = (const float*)d_in[6];
    const float* W3 = (const float*)d_in[7];
    const float* b3 = (const float*)d_in[8];
    const float* W4 = (const float*)d_in[9];
    const float* b4 = (const float*)d_in[10];
    float* out = (float*)d_out;

    char* ws = (char*)d_ws;
    // workspace layout (bytes, 256-aligned)
    float*          dinv    = (float*)(ws + 0);                  // 40,000
    int*            cnt     = (int*)  (ws + 40960);
    int*            row_cnt = (int*)  (ws + 81920);
    int*            row_ptr = (int*)  (ws + 122880);             // 40,004
    int*            col_src = (int*)  (ws + 163840);             // 640,000
    float*          Y4      = (float*)(ws + 803840);             // 80,000
    unsigned short* xb      = (unsigned short*)(ws + 884224);    // MPAD*K1PAD*2 = 45,301,760
    unsigned short* W1t     = (unsigned short*)(ws + 46185984);  // 512*K1PAD*2 = 2,293,760
    unsigned short* W2t     = (unsigned short*)(ws + 48479744);  // 524,288
    unsigned short* W3t     = (unsigned short*)(ws + 49004032);  // 524,288
    float*          Yf      = (float*)(ws + 49528320);           // MPAD*512*4 = 20,709,376
    unsigned short* Hb      = (unsigned short*)(ws + 70237696);  // MPAD*512*2 = 10,354,688
    // total: 80,592,384 bytes
    if (ws_size < 80592384) return;

    // graph preprocessing
    k_init<<<40, 256, 0, stream>>>(cnt, row_cnt, NNODES);
    k_hist<<<625, 256, 0, stream>>>(ei, cnt, NEDGES);
    k_scan<<<1, 1024, 0, stream>>>(cnt, row_ptr, NNODES);
    k_dinv<<<40, 256, 0, stream>>>(cnt, dinv, NNODES);
    k_fill<<<625, 256, 0, stream>>>(ei, row_ptr, row_cnt, col_src, NEDGES);

    // bf16 conversions
    k_cvt_x<<<dim3(9, MPAD), 256, 0, stream>>>(x, xb);
    k_cvt_wt<<<dim3(9, HDIM), 256, 0, stream>>>(W1, W1t, FIN, K1PAD);
    k_cvt_wt<<<dim3(2, HDIM), 256, 0, stream>>>(W2, W2t, HDIM, HDIM);
    k_cvt_wt<<<dim3(2, HDIM), 256, 0, stream>>>(W3, W3t, HDIM, HDIM);

    dim3 ggrid(MPAD / 128, 4);   // 79 x 4

    // layer 1
    k_gemm_bf16<<<ggrid, 256, 0, stream>>>(xb, W1t, Yf, NNODES, K1PAD);
    k_agg<<<(MPAD * 64) / 256, 256, 0, stream>>>(Yf, dinv, row_ptr, col_src, b1, Hb, 1);
    // layer 2
    k_gemm_bf16<<<ggrid, 256, 0, stream>>>(Hb, W2t, Yf, NNODES, HDIM);
    k_agg<<<(MPAD * 64) / 256, 256, 0, stream>>>(Yf, dinv, row_ptr, col_src, b2, Hb, 1);
    // layer 3
    k_gemm_bf16<<<ggrid, 256, 0, stream>>>(Hb, W3t, Yf, NNODES, HDIM);
    k_agg<<<(MPAD * 64) / 256, 256, 0, stream>>>(Yf, dinv, row_ptr, col_src, b3, Hb, 1);
    // layer 4 + log_softmax
    k_gemm4<<<2500, 256, 0, stream>>>(Hb, W4, Y4, NNODES);
    k_final<<<40, 256, 0, stream>>>(Y4, dinv, row_ptr, col_src, b4, out, NNODES);
}

// Round 3
// 367.514 us; speedup vs baseline: 2.4276x; 1.2817x over previous
//
#include <hip/hip_runtime.h>
#include <hip/hip_bf16.h>

// Problem constants (fixed by the reference).
#define NNODES 10000
#define NEDGES 160000
#define FIN    2208
#define HDIM   512
#define NCLS   2

#define MPAD   10240     // 80 * 128 -> grid 80x4 = 320 blocks, even XCD groups
#define K1PAD  2240      // 2208 padded to multiple of 64

typedef __bf16 bf16x8 __attribute__((ext_vector_type(8)));
typedef float  f32x4  __attribute__((ext_vector_type(4)));
typedef unsigned short u16x8 __attribute__((ext_vector_type(8)));

__device__ inline unsigned short f2bf(float f) {
    union { float f; unsigned int u; } v; v.f = f;
    return (unsigned short)((v.u + 0x7FFFu + ((v.u >> 16) & 1u)) >> 16);
}
__device__ inline float bf2f(unsigned short u) {
    union { unsigned int i; float f; } v; v.i = ((unsigned int)u) << 16; return v.f;
}

// ---------------- graph preprocessing ----------------

__global__ void k_init(int* cnt, int* row_cnt, int n) {
    int i = blockIdx.x * blockDim.x + threadIdx.x;
    if (i < n) { cnt[i] = 0; row_cnt[i] = 0; }
}

__global__ void k_hist(const int* __restrict__ ei, int* __restrict__ cnt, int e) {
    int i = blockIdx.x * blockDim.x + threadIdx.x;
    if (i < e) atomicAdd(&cnt[ei[NEDGES + i]], 1);
}

// single-block scan, wave-shuffle based. row_ptr[0]=0, row_ptr[i+1]=incl[i]
__global__ void k_scan(const int* __restrict__ cnt, int* __restrict__ row_ptr, int n) {
    __shared__ int wsum[16];
    __shared__ int s_carry;
    int tid = threadIdx.x;
    int lane = tid & 63, wid = tid >> 6;
    if (tid == 0) { s_carry = 0; row_ptr[0] = 0; }
    __syncthreads();
    for (int base = 0; base < n; base += 1024) {
        int i = base + tid;
        int v = (i < n) ? cnt[i] : 0;
        #pragma unroll
        for (int off = 1; off < 64; off <<= 1) {
            int t = __shfl_up(v, off);
            if (lane >= off) v += t;
        }
        if (lane == 63) wsum[wid] = v;
        __syncthreads();
        if (wid == 0) {
            int s = (lane < 16) ? wsum[lane] : 0;
            #pragma unroll
            for (int off = 1; off < 16; off <<= 1) {
                int t = __shfl_up(s, off);
                if (lane >= off) s += t;
            }
            if (lane < 16) wsum[lane] = s;
        }
        __syncthreads();
        int add = s_carry + ((wid > 0) ? wsum[wid - 1] : 0);
        if (i < n) row_ptr[i + 1] = v + add;
        __syncthreads();
        if (tid == 1023) s_carry += wsum[15];
        __syncthreads();
    }
}

__global__ void k_dinv(const int* __restrict__ cnt, float* __restrict__ dinv, int n) {
    int i = blockIdx.x * blockDim.x + threadIdx.x;
    if (i < n) dinv[i] = rsqrtf((float)cnt[i] + 1.0f);
}

__global__ void k_fill(const int* __restrict__ ei, const int* __restrict__ row_ptr,
                       int* __restrict__ row_cnt, int* __restrict__ col_src, int e) {
    int i = blockIdx.x * blockDim.x + threadIdx.x;
    if (i < e) {
        int src = ei[i];
        int dst = ei[NEDGES + i];
        int pos = row_ptr[dst] + atomicAdd(&row_cnt[dst], 1);
        col_src[pos] = src;
    }
}

// ---------------- converters ----------------

// x fp32 [10000][2208] -> xb bf16 [MPAD][K1PAD], zero-padded. One block per row.
__global__ void k_cvt_x(const float* __restrict__ x, unsigned short* __restrict__ xb) {
    int row = blockIdx.x;
    int t = threadIdx.x;
    unsigned short* orow = xb + (size_t)row * K1PAD;
    u16x8 z = {0, 0, 0, 0, 0, 0, 0, 0};
    if (row >= NNODES) {
        for (int c = t; c < K1PAD / 8; c += 256) *(u16x8*)(orow + c * 8) = z;
        return;
    }
    const float* irow = x + (size_t)row * FIN;
    for (int c = t; c < K1PAD / 8; c += 256) {
        int col = c * 8;
        u16x8 o = z;
        if (col + 8 <= FIN) {   // FIN=2208 divisible by 8 -> clean boundary
            float4 f0 = *(const float4*)(irow + col);
            float4 f1 = *(const float4*)(irow + col + 4);
            o[0] = f2bf(f0.x); o[1] = f2bf(f0.y); o[2] = f2bf(f0.z); o[3] = f2bf(f0.w);
            o[4] = f2bf(f1.x); o[5] = f2bf(f1.y); o[6] = f2bf(f1.z); o[7] = f2bf(f1.w);
        }
        *(u16x8*)(orow + col) = o;
    }
}

// W fp32 [K][512] -> Wt bf16 [512][Kp], zero-padded in k
__global__ void k_cvt_wt(const float* __restrict__ W, unsigned short* __restrict__ Wt,
                         int Kreal, int Kp) {
    int k = blockIdx.x * 256 + threadIdx.x;
    int n = blockIdx.y;
    if (k >= Kp) return;
    float v = (k < Kreal) ? W[(size_t)k * HDIM + n] : 0.0f;
    Wt[(size_t)n * Kp + k] = f2bf(v);
}

// ---------------- bf16 MFMA GEMM: C[M,512] = A[M,K] @ Bt[512,K]^T, bf16 out ----
// 128x128 tile, BK=64, 4 waves 2x2, XOR-swizzled LDS, global_load_lds width 16.
// Grid is linear (320); decode groups the 4 bn-blocks of one bm-strip onto the
// same XCD (dispatch round-robins blockIdx%8) so the A strip is fetched into
// that XCD's L2 once and reused 4x.

#define BKK 64

__global__ __launch_bounds__(256) void k_gemm_bf16(
    const unsigned short* __restrict__ A,   // [MPAD][K] bf16
    const unsigned short* __restrict__ Bt,  // [512][K] bf16 (W transposed)
    unsigned short* __restrict__ C,         // [MPAD][512] bf16
    int M, int K) {
    __shared__ char As[128 * BKK * 2] __attribute__((aligned(16)));  // 16 KB
    __shared__ char Bs[128 * BKK * 2] __attribute__((aligned(16)));  // 16 KB
    const int tid  = threadIdx.x;
    const int lane = tid & 63;
    const int w    = tid >> 6;
    const int wm   = w & 1, wn = w >> 1;
    const int quad = lane >> 4, lq = lane & 15;

    // XCD-grouped decode: l%8 = xcd slot; strip*8+xcd = bm tile; j&3 = bn tile
    const int l    = blockIdx.x;            // 0..319
    const int xcd  = l & 7;
    const int j    = l >> 3;                // 0..39
    const int bm   = ((j >> 2) * 8 + xcd) * 128;
    const int bn   = (j & 3) * 128;

    f32x4 acc[4][4] = {};

    for (int k0 = 0; k0 < K; k0 += BKK) {
        #pragma unroll
        for (int i = 0; i < 4; ++i) {
            int c  = i * 256 + tid;
            int r  = c >> 3;
            int g  = (c & 7) ^ (r & 7);     // XOR swizzle
            const char* gpA = (const char*)A  + ((size_t)(bm + r) * K + k0) * 2 + (g << 4);
            const char* gpB = (const char*)Bt + ((size_t)(bn + r) * K + k0) * 2 + (g << 4);
            __builtin_amdgcn_global_load_lds(
                (const __attribute__((address_space(1))) void*)gpA,
                (__attribute__((address_space(3))) void*)(As + c * 16), 16, 0, 0);
            __builtin_amdgcn_global_load_lds(
                (const __attribute__((address_space(1))) void*)gpB,
                (__attribute__((address_space(3))) void*)(Bs + c * 16), 16, 0, 0);
        }
        __syncthreads();

        #pragma unroll
        for (int s = 0; s < 2; ++s) {
            bf16x8 af[4], bfr[4];
            #pragma unroll
            for (int i = 0; i < 4; ++i) {
                int r = wm * 64 + i * 16 + lq;
                int g = s * 4 + quad;
                af[i]  = *(const bf16x8*)(As + r * 128 + ((g ^ (r & 7)) << 4));
                int n = wn * 64 + i * 16 + lq;
                bfr[i] = *(const bf16x8*)(Bs + n * 128 + ((g ^ (n & 7)) << 4));
            }
            #pragma unroll
            for (int i = 0; i < 4; ++i)
                #pragma unroll
                for (int jj = 0; jj < 4; ++jj)
                    acc[i][jj] = __builtin_amdgcn_mfma_f32_16x16x32_bf16(
                        af[i], bfr[jj], acc[i][jj], 0, 0, 0);
        }
        __syncthreads();
    }

    // C/D layout: col = lane&15, row = quad*4 + reg
    #pragma unroll
    for (int i = 0; i < 4; ++i) {
        #pragma unroll
        for (int p = 0; p < 4; ++p) {
            int r = bm + wm * 64 + i * 16 + quad * 4 + p;
            if (r < M) {
                #pragma unroll
                for (int jj = 0; jj < 4; ++jj) {
                    int col = bn + wn * 64 + jj * 16 + lq;
                    C[(size_t)r * HDIM + col] = f2bf(acc[i][jj][p]);
                }
            }
        }
    }
}

// ---------------- aggregation: bf16 in, fp32 accumulate, bf16 out ----------------
// Hb[d] = bf16( relu( dinv[d]^2*Y[d] + sum_s dinv[d]dinv[s]*Y[s] + b ) )
// One wave per node; each lane owns 8 contiguous features (16B). 4-edge unroll.

__global__ void k_agg(const unsigned short* __restrict__ Y, const float* __restrict__ dinv,
                      const int* __restrict__ row_ptr, const int* __restrict__ col_src,
                      const float* __restrict__ bias, unsigned short* __restrict__ Hb,
                      int do_relu) {
    int w = (blockIdx.x * blockDim.x + threadIdx.x) >> 6;
    int lane = threadIdx.x & 63;
    if (w >= MPAD) return;
    unsigned short* hr = Hb + (size_t)w * HDIM + lane * 8;
    if (w >= NNODES) {
        u16x8 z = {0, 0, 0, 0, 0, 0, 0, 0};
        *(u16x8*)hr = z;
        return;
    }
    float di = dinv[w];
    float sw = di * di;
    u16x8 own = *(const u16x8*)(Y + (size_t)w * HDIM + lane * 8);
    float acc[8];
    #pragma unroll
    for (int t = 0; t < 8; ++t) acc[t] = sw * bf2f(own[t]);

    int e0 = row_ptr[w], e1 = row_ptr[w + 1];
    int e = e0;
    for (; e + 4 <= e1; e += 4) {
        int s0 = col_src[e + 0], s1 = col_src[e + 1];
        int s2 = col_src[e + 2], s3 = col_src[e + 3];
        float w0 = di * dinv[s0], w1 = di * dinv[s1];
        float w2 = di * dinv[s2], w3 = di * dinv[s3];
        u16x8 v0 = *(const u16x8*)(Y + (size_t)s0 * HDIM + lane * 8);
        u16x8 v1 = *(const u16x8*)(Y + (size_t)s1 * HDIM + lane * 8);
        u16x8 v2 = *(const u16x8*)(Y + (size_t)s2 * HDIM + lane * 8);
        u16x8 v3 = *(const u16x8*)(Y + (size_t)s3 * HDIM + lane * 8);
        #pragma unroll
        for (int t = 0; t < 8; ++t) {
            acc[t] += w0 * bf2f(v0[t]);
            acc[t] += w1 * bf2f(v1[t]);
            acc[t] += w2 * bf2f(v2[t]);
            acc[t] += w3 * bf2f(v3[t]);
        }
    }
    for (; e < e1; ++e) {
        int s = col_src[e];
        float wg = di * dinv[s];
        u16x8 v = *(const u16x8*)(Y + (size_t)s * HDIM + lane * 8);
        #pragma unroll
        for (int t = 0; t < 8; ++t) acc[t] += wg * bf2f(v[t]);
    }

    float4 b0 = ((const float4*)bias)[lane * 2];
    float4 b1 = ((const float4*)bias)[lane * 2 + 1];
    acc[0] += b0.x; acc[1] += b0.y; acc[2] += b0.z; acc[3] += b0.w;
    acc[4] += b1.x; acc[5] += b1.y; acc[6] += b1.z; acc[7] += b1.w;
    u16x8 o;
    #pragma unroll
    for (int t = 0; t < 8; ++t) {
        float v = acc[t];
        if (do_relu) v = fmaxf(v, 0.0f);
        o[t] = f2bf(v);
    }
    *(u16x8*)hr = o;
}

// ---------------- layer-4 GEMM (bf16 H, K=512, N=2): one wave per row ----------------

__global__ void k_gemm4(const unsigned short* __restrict__ H, const float* __restrict__ W4,
                        float* __restrict__ Y4, int n) {
    int w = (blockIdx.x * blockDim.x + threadIdx.x) >> 6;
    int lane = threadIdx.x & 63;
    if (w >= n) return;
    const unsigned short* hr = H + (size_t)w * HDIM + lane * 8;
    ushort4 hA = *(const ushort4*)hr;
    ushort4 hB = *(const ushort4*)(hr + 4);
    float hv[8] = {bf2f(hA.x), bf2f(hA.y), bf2f(hA.z), bf2f(hA.w),
                   bf2f(hB.x), bf2f(hB.y), bf2f(hB.z), bf2f(hB.w)};
    const float4* wf = (const float4*)W4;  // [k][c] flat
    float4 w0 = wf[lane * 4 + 0];
    float4 w1 = wf[lane * 4 + 1];
    float4 w2 = wf[lane * 4 + 2];
    float4 w3 = wf[lane * 4 + 3];
    float acc0 = hv[0]*w0.x + hv[1]*w0.z + hv[2]*w1.x + hv[3]*w1.z
               + hv[4]*w2.x + hv[5]*w2.z + hv[6]*w3.x + hv[7]*w3.z;
    float acc1 = hv[0]*w0.y + hv[1]*w0.w + hv[2]*w1.y + hv[3]*w1.w
               + hv[4]*w2.y + hv[5]*w2.w + hv[6]*w3.y + hv[7]*w3.w;
    #pragma unroll
    for (int off = 32; off > 0; off >>= 1) {
        acc0 += __shfl_down(acc0, off);
        acc1 += __shfl_down(acc1, off);
    }
    if (lane == 0) {
        Y4[2 * w] = acc0;
        Y4[2 * w + 1] = acc1;
    }
}

// ---------------- layer-4 aggregation + bias + log_softmax ----------------

__global__ void k_final(const float* __restrict__ Y4, const float* __restrict__ dinv,
                        const int* __restrict__ row_ptr, const int* __restrict__ col_src,
                        const float* __restrict__ b4, float* __restrict__ out, int n) {
    int i = blockIdx.x * blockDim.x + threadIdx.x;
    if (i >= n) return;
    float di = dinv[i];
    float sw = di * di;
    float z0 = sw * Y4[2 * i];
    float z1 = sw * Y4[2 * i + 1];
    int e0 = row_ptr[i], e1 = row_ptr[i + 1];
    for (int e = e0; e < e1; ++e) {
        int s = col_src[e];
        float wgt = di * dinv[s];
        z0 += wgt * Y4[2 * s];
        z1 += wgt * Y4[2 * s + 1];
    }
    z0 += b4[0];
    z1 += b4[1];
    float m = fmaxf(z0, z1);
    float l = m + logf(expf(z0 - m) + expf(z1 - m));
    out[2 * i] = z0 - l;
    out[2 * i + 1] = z1 - l;
}

// ---------------- launch ----------------

extern "C" void kernel_launch(void* const* d_in, const int* in_sizes, int n_in,
                              void* d_out, int out_size, void* d_ws, size_t ws_size,
                              hipStream_t stream) {
    const float* x  = (const float*)d_in[0];
    const int*   ei = (const int*)d_in[1];
    const float* W1 = (const float*)d_in[3];
    const float* b1 = (const float*)d_in[4];
    const float* W2 = (const float*)d_in[5];
    const float* b2 = (const float*)d_in[6];
    const float* W3 = (const float*)d_in[7];
    const float* b3 = (const float*)d_in[8];
    const float* W4 = (const float*)d_in[9];
    const float* b4 = (const float*)d_in[10];
    float* out = (float*)d_out;

    char* ws = (char*)d_ws;
    // workspace layout (bytes, 256-aligned)
    float*          dinv    = (float*)(ws + 0);                  // 40,000
    int*            cnt     = (int*)  (ws + 40960);
    int*            row_cnt = (int*)  (ws + 81920);
    int*            row_ptr = (int*)  (ws + 122880);             // 40,004
    int*            col_src = (int*)  (ws + 163840);             // 640,000
    float*          Y4      = (float*)(ws + 803840);             // 80,000
    unsigned short* xb      = (unsigned short*)(ws + 884224);    // MPAD*K1PAD*2 = 45,875,200
    unsigned short* W1t     = (unsigned short*)(ws + 46759424);  // 2,293,760
    unsigned short* W2t     = (unsigned short*)(ws + 49053184);  // 524,288
    unsigned short* W3t     = (unsigned short*)(ws + 49577472);  // 524,288
    unsigned short* Yb      = (unsigned short*)(ws + 50101760);  // MPAD*512*2 = 10,485,760
    unsigned short* Hb      = (unsigned short*)(ws + 60587520);  // 10,485,760
    // total: 71,073,280 bytes
    if (ws_size < 71073280) return;

    // graph preprocessing
    k_init<<<40, 256, 0, stream>>>(cnt, row_cnt, NNODES);
    k_hist<<<625, 256, 0, stream>>>(ei, cnt, NEDGES);
    k_scan<<<1, 1024, 0, stream>>>(cnt, row_ptr, NNODES);
    k_dinv<<<40, 256, 0, stream>>>(cnt, dinv, NNODES);
    k_fill<<<625, 256, 0, stream>>>(ei, row_ptr, row_cnt, col_src, NEDGES);

    // bf16 conversions
    k_cvt_x<<<MPAD, 256, 0, stream>>>(x, xb);
    k_cvt_wt<<<dim3(9, HDIM), 256, 0, stream>>>(W1, W1t, FIN, K1PAD);
    k_cvt_wt<<<dim3(2, HDIM), 256, 0, stream>>>(W2, W2t, HDIM, HDIM);
    k_cvt_wt<<<dim3(2, HDIM), 256, 0, stream>>>(W3, W3t, HDIM, HDIM);

    const int ggrid = (MPAD / 128) * 4;   // 320 linear blocks, XCD-grouped decode
    const int agrid = (MPAD * 64) / 256;  // one wave per (padded) node

    // layer 1
    k_gemm_bf16<<<ggrid, 256, 0, stream>>>(xb, W1t, Yb, NNODES, K1PAD);
    k_agg<<<agrid, 256, 0, stream>>>(Yb, dinv, row_ptr, col_src, b1, Hb, 1);
    // layer 2
    k_gemm_bf16<<<ggrid, 256, 0, stream>>>(Hb, W2t, Yb, NNODES, HDIM);
    k_agg<<<agrid, 256, 0, stream>>>(Yb, dinv, row_ptr, col_src, b2, Hb, 1);
    // layer 3
    k_gemm_bf16<<<ggrid, 256, 0, stream>>>(Hb, W3t, Yb, NNODES, HDIM);
    k_agg<<<agrid, 256, 0, stream>>>(Yb, dinv, row_ptr, col_src, b3, Hb, 1);
    // layer 4 + log_softmax
    k_gemm4<<<2500, 256, 0, stream>>>(Hb, W4, Y4, NNODES);
    k_final<<<40, 256, 0, stream>>>(Y4, dinv, row_ptr, col_src, b4, out, NNODES);
}

// Round 4
// 345.960 us; speedup vs baseline: 2.5789x; 1.0623x over previous
//
#include <hip/hip_runtime.h>
#include <hip/hip_bf16.h>

// Problem constants (fixed by the reference).
#define NNODES 10000
#define NEDGES 160000
#define FIN    2208
#define HDIM   512
#define NCLS   2

#define MPAD   10240     // 80 * 128
#define K1PAD  2240      // 2208 padded to multiple of 64

typedef __bf16 bf16x8 __attribute__((ext_vector_type(8)));
typedef float  f32x4  __attribute__((ext_vector_type(4)));
typedef unsigned short u16x8 __attribute__((ext_vector_type(8)));

__device__ inline unsigned short f2bf(float f) {
    union { float f; unsigned int u; } v; v.f = f;
    return (unsigned short)((v.u + 0x7FFFu + ((v.u >> 16) & 1u)) >> 16);
}
__device__ inline float bf2f(unsigned short u) {
    union { unsigned int i; float f; } v; v.i = ((unsigned int)u) << 16; return v.f;
}

// ---------------- graph preprocessing ----------------

__global__ void k_init(int* cnt, int* row_cnt, int n) {
    int i = blockIdx.x * blockDim.x + threadIdx.x;
    if (i < n) { cnt[i] = 0; row_cnt[i] = 0; }
}

__global__ void k_hist(const int* __restrict__ ei, int* __restrict__ cnt, int e) {
    int i = blockIdx.x * blockDim.x + threadIdx.x;
    if (i < e) atomicAdd(&cnt[ei[NEDGES + i]], 1);
}

// single-block scan (wave-shuffle) + dinv fold. row_ptr[0]=0, row_ptr[i+1]=incl[i]
__global__ void k_scan(const int* __restrict__ cnt, int* __restrict__ row_ptr,
                       float* __restrict__ dinv, int n) {
    __shared__ int wsum[16];
    __shared__ int s_carry;
    int tid = threadIdx.x;
    int lane = tid & 63, wid = tid >> 6;
    if (tid == 0) { s_carry = 0; row_ptr[0] = 0; }
    __syncthreads();
    for (int base = 0; base < n; base += 1024) {
        int i = base + tid;
        int deg = (i < n) ? cnt[i] : 0;
        if (i < n) dinv[i] = rsqrtf((float)deg + 1.0f);
        int v = deg;
        #pragma unroll
        for (int off = 1; off < 64; off <<= 1) {
            int t = __shfl_up(v, off);
            if (lane >= off) v += t;
        }
        if (lane == 63) wsum[wid] = v;
        __syncthreads();
        if (wid == 0) {
            int s = (lane < 16) ? wsum[lane] : 0;
            #pragma unroll
            for (int off = 1; off < 16; off <<= 1) {
                int t = __shfl_up(s, off);
                if (lane >= off) s += t;
            }
            if (lane < 16) wsum[lane] = s;
        }
        __syncthreads();
        int add = s_carry + ((wid > 0) ? wsum[wid - 1] : 0);
        if (i < n) row_ptr[i + 1] = v + add;
        __syncthreads();
        if (tid == 1023) s_carry += wsum[15];
        __syncthreads();
    }
}

__global__ void k_fill(const int* __restrict__ ei, const int* __restrict__ row_ptr,
                       int* __restrict__ row_cnt, int* __restrict__ col_src, int e) {
    int i = blockIdx.x * blockDim.x + threadIdx.x;
    if (i < e) {
        int src = ei[i];
        int dst = ei[NEDGES + i];
        int pos = row_ptr[dst] + atomicAdd(&row_cnt[dst], 1);
        col_src[pos] = src;
    }
}

// ---------------- converters ----------------

// x fp32 [10000][2208] -> xb bf16 [MPAD][K1PAD], zero-padded. One block per row.
__global__ void k_cvt_x(const float* __restrict__ x, unsigned short* __restrict__ xb) {
    int row = blockIdx.x;
    int t = threadIdx.x;
    unsigned short* orow = xb + (size_t)row * K1PAD;
    u16x8 z = {0, 0, 0, 0, 0, 0, 0, 0};
    if (row >= NNODES) {
        for (int c = t; c < K1PAD / 8; c += 256) *(u16x8*)(orow + c * 8) = z;
        return;
    }
    const float* irow = x + (size_t)row * FIN;
    for (int c = t; c < K1PAD / 8; c += 256) {
        int col = c * 8;
        u16x8 o = z;
        if (col + 8 <= FIN) {   // FIN=2208 divisible by 8 -> clean boundary
            float4 f0 = *(const float4*)(irow + col);
            float4 f1 = *(const float4*)(irow + col + 4);
            o[0] = f2bf(f0.x); o[1] = f2bf(f0.y); o[2] = f2bf(f0.z); o[3] = f2bf(f0.w);
            o[4] = f2bf(f1.x); o[5] = f2bf(f1.y); o[6] = f2bf(f1.z); o[7] = f2bf(f1.w);
        }
        *(u16x8*)(orow + col) = o;
    }
}

// all three weight transposes in one dispatch. grid (13, 512).
__global__ void k_cvt_w(const float* __restrict__ W1, const float* __restrict__ W2,
                        const float* __restrict__ W3, unsigned short* __restrict__ W1t,
                        unsigned short* __restrict__ W2t, unsigned short* __restrict__ W3t) {
    int n = blockIdx.y;
    int bx = blockIdx.x;
    int t = threadIdx.x;
    if (bx < 9) {
        int k = bx * 256 + t;
        if (k < K1PAD) {
            float v = (k < FIN) ? W1[(size_t)k * HDIM + n] : 0.0f;
            W1t[(size_t)n * K1PAD + k] = f2bf(v);
        }
    } else if (bx < 11) {
        int k = (bx - 9) * 256 + t;
        W2t[(size_t)n * HDIM + k] = f2bf(W2[(size_t)k * HDIM + n]);
    } else {
        int k = (bx - 11) * 256 + t;
        W3t[(size_t)n * HDIM + k] = f2bf(W3[(size_t)k * HDIM + n]);
    }
}

// ---------------- bf16 MFMA GEMM: C[M,512] = A[M,K] @ Bt[512,K]^T, bf16 out ----
// Tile 128(M) x 64(N), BK=64. Grid 640 linear (2.5 blocks/CU -> better balance
// than 320 @ 1.25). 4 waves 2x2; wave tile 64x32 (acc 4x2). XOR-swizzled LDS,
// global_load_lds width 16. Decode keeps one strip's 8 n-tiles on one XCD so
// the A strip lives in that XCD's L2 (B is weight, L2-resident everywhere).

#define BKK 64

__global__ __launch_bounds__(256) void k_gemm_bf16(
    const unsigned short* __restrict__ A,   // [MPAD][K] bf16
    const unsigned short* __restrict__ Bt,  // [512][K] bf16 (W transposed)
    unsigned short* __restrict__ C,         // [MPAD][512] bf16
    int M, int K) {
    __shared__ char As[128 * BKK * 2] __attribute__((aligned(16)));  // 16 KB
    __shared__ char Bs[64 * BKK * 2]  __attribute__((aligned(16)));  // 8 KB
    const int tid  = threadIdx.x;
    const int lane = tid & 63;
    const int w    = tid >> 6;
    const int wm   = w & 1, wn = w >> 1;
    const int quad = lane >> 4, lq = lane & 15;

    // decode: xcd slot = l&7; q=l>>3: strip = (q>>3)*8+xcd, ntile = q&7
    const int l     = blockIdx.x;           // 0..639
    const int xcd   = l & 7;
    const int q     = l >> 3;               // 0..79
    const int strip = (q >> 3) * 8 + xcd;   // 0..79
    const int bm    = strip * 128;
    const int bn    = (q & 7) * 64;

    f32x4 acc[4][2] = {};

    for (int k0 = 0; k0 < K; k0 += BKK) {
        // A: 1024 16B chunks (4/thread); B: 512 chunks (2/thread)
        #pragma unroll
        for (int i = 0; i < 4; ++i) {
            int c  = i * 256 + tid;
            int r  = c >> 3;
            int g  = (c & 7) ^ (r & 7);     // XOR swizzle (source-side)
            const char* gpA = (const char*)A + ((size_t)(bm + r) * K + k0) * 2 + (g << 4);
            __builtin_amdgcn_global_load_lds(
                (const __attribute__((address_space(1))) void*)gpA,
                (__attribute__((address_space(3))) void*)(As + c * 16), 16, 0, 0);
        }
        #pragma unroll
        for (int i = 0; i < 2; ++i) {
            int c  = i * 256 + tid;
            int r  = c >> 3;
            int g  = (c & 7) ^ (r & 7);
            const char* gpB = (const char*)Bt + ((size_t)(bn + r) * K + k0) * 2 + (g << 4);
            __builtin_amdgcn_global_load_lds(
                (const __attribute__((address_space(1))) void*)gpB,
                (__attribute__((address_space(3))) void*)(Bs + c * 16), 16, 0, 0);
        }
        __syncthreads();

        #pragma unroll
        for (int s = 0; s < 2; ++s) {
            bf16x8 af[4], bfr[2];
            int g = s * 4 + quad;
            #pragma unroll
            for (int i = 0; i < 4; ++i) {
                int r = wm * 64 + i * 16 + lq;
                af[i] = *(const bf16x8*)(As + r * 128 + ((g ^ (r & 7)) << 4));
            }
            #pragma unroll
            for (int j = 0; j < 2; ++j) {
                int n = wn * 32 + j * 16 + lq;
                bfr[j] = *(const bf16x8*)(Bs + n * 128 + ((g ^ (n & 7)) << 4));
            }
            #pragma unroll
            for (int i = 0; i < 4; ++i)
                #pragma unroll
                for (int j = 0; j < 2; ++j)
                    acc[i][j] = __builtin_amdgcn_mfma_f32_16x16x32_bf16(
                        af[i], bfr[j], acc[i][j], 0, 0, 0);
        }
        __syncthreads();
    }

    // C/D layout: col = lane&15, row = quad*4 + reg
    #pragma unroll
    for (int i = 0; i < 4; ++i) {
        #pragma unroll
        for (int p = 0; p < 4; ++p) {
            int r = bm + wm * 64 + i * 16 + quad * 4 + p;
            if (r < M) {
                #pragma unroll
                for (int j = 0; j < 2; ++j) {
                    int col = bn + wn * 32 + j * 16 + lq;
                    C[(size_t)r * HDIM + col] = f2bf(acc[i][j][p]);
                }
            }
        }
    }
}

// ---------------- aggregation: bf16 in, fp32 accumulate, bf16 out ----------------

__global__ void k_agg(const unsigned short* __restrict__ Y, const float* __restrict__ dinv,
                      const int* __restrict__ row_ptr, const int* __restrict__ col_src,
                      const float* __restrict__ bias, unsigned short* __restrict__ Hb,
                      int do_relu) {
    int w = (blockIdx.x * blockDim.x + threadIdx.x) >> 6;
    int lane = threadIdx.x & 63;
    if (w >= MPAD) return;
    unsigned short* hr = Hb + (size_t)w * HDIM + lane * 8;
    if (w >= NNODES) {
        u16x8 z = {0, 0, 0, 0, 0, 0, 0, 0};
        *(u16x8*)hr = z;
        return;
    }
    float di = dinv[w];
    float sw = di * di;
    u16x8 own = *(const u16x8*)(Y + (size_t)w * HDIM + lane * 8);
    float acc[8];
    #pragma unroll
    for (int t = 0; t < 8; ++t) acc[t] = sw * bf2f(own[t]);

    int e0 = row_ptr[w], e1 = row_ptr[w + 1];
    int e = e0;
    for (; e + 4 <= e1; e += 4) {
        int s0 = col_src[e + 0], s1 = col_src[e + 1];
        int s2 = col_src[e + 2], s3 = col_src[e + 3];
        float w0 = di * dinv[s0], w1 = di * dinv[s1];
        float w2 = di * dinv[s2], w3 = di * dinv[s3];
        u16x8 v0 = *(const u16x8*)(Y + (size_t)s0 * HDIM + lane * 8);
        u16x8 v1 = *(const u16x8*)(Y + (size_t)s1 * HDIM + lane * 8);
        u16x8 v2 = *(const u16x8*)(Y + (size_t)s2 * HDIM + lane * 8);
        u16x8 v3 = *(const u16x8*)(Y + (size_t)s3 * HDIM + lane * 8);
        #pragma unroll
        for (int t = 0; t < 8; ++t) {
            acc[t] += w0 * bf2f(v0[t]);
            acc[t] += w1 * bf2f(v1[t]);
            acc[t] += w2 * bf2f(v2[t]);
            acc[t] += w3 * bf2f(v3[t]);
        }
    }
    for (; e < e1; ++e) {
        int s = col_src[e];
        float wg = di * dinv[s];
        u16x8 v = *(const u16x8*)(Y + (size_t)s * HDIM + lane * 8);
        #pragma unroll
        for (int t = 0; t < 8; ++t) acc[t] += wg * bf2f(v[t]);
    }

    float4 b0 = ((const float4*)bias)[lane * 2];
    float4 b1 = ((const float4*)bias)[lane * 2 + 1];
    acc[0] += b0.x; acc[1] += b0.y; acc[2] += b0.z; acc[3] += b0.w;
    acc[4] += b1.x; acc[5] += b1.y; acc[6] += b1.z; acc[7] += b1.w;
    u16x8 o;
    #pragma unroll
    for (int t = 0; t < 8; ++t) {
        float v = acc[t];
        if (do_relu) v = fmaxf(v, 0.0f);
        o[t] = f2bf(v);
    }
    *(u16x8*)hr = o;
}

// ---------------- layer-4 GEMM (bf16 H, K=512, N=2): one wave per row ----------------

__global__ void k_gemm4(const unsigned short* __restrict__ H, const float* __restrict__ W4,
                        float* __restrict__ Y4, int n) {
    int w = (blockIdx.x * blockDim.x + threadIdx.x) >> 6;
    int lane = threadIdx.x & 63;
    if (w >= n) return;
    const unsigned short* hr = H + (size_t)w * HDIM + lane * 8;
    ushort4 hA = *(const ushort4*)hr;
    ushort4 hB = *(const ushort4*)(hr + 4);
    float hv[8] = {bf2f(hA.x), bf2f(hA.y), bf2f(hA.z), bf2f(hA.w),
                   bf2f(hB.x), bf2f(hB.y), bf2f(hB.z), bf2f(hB.w)};
    const float4* wf = (const float4*)W4;  // [k][c] flat
    float4 w0 = wf[lane * 4 + 0];
    float4 w1 = wf[lane * 4 + 1];
    float4 w2 = wf[lane * 4 + 2];
    float4 w3 = wf[lane * 4 + 3];
    float acc0 = hv[0]*w0.x + hv[1]*w0.z + hv[2]*w1.x + hv[3]*w1.z
               + hv[4]*w2.x + hv[5]*w2.z + hv[6]*w3.x + hv[7]*w3.z;
    float acc1 = hv[0]*w0.y + hv[1]*w0.w + hv[2]*w1.y + hv[3]*w1.w
               + hv[4]*w2.y + hv[5]*w2.w + hv[6]*w3.y + hv[7]*w3.w;
    #pragma unroll
    for (int off = 32; off > 0; off >>= 1) {
        acc0 += __shfl_down(acc0, off);
        acc1 += __shfl_down(acc1, off);
    }
    if (lane == 0) {
        Y4[2 * w] = acc0;
        Y4[2 * w + 1] = acc1;
    }
}

// ---------------- layer-4 aggregation + bias + log_softmax ----------------

__global__ void k_final(const float* __restrict__ Y4, const float* __restrict__ dinv,
                        const int* __restrict__ row_ptr, const int* __restrict__ col_src,
                        const float* __restrict__ b4, float* __restrict__ out, int n) {
    int i = blockIdx.x * blockDim.x + threadIdx.x;
    if (i >= n) return;
    float di = dinv[i];
    float sw = di * di;
    float z0 = sw * Y4[2 * i];
    float z1 = sw * Y4[2 * i + 1];
    int e0 = row_ptr[i], e1 = row_ptr[i + 1];
    for (int e = e0; e < e1; ++e) {
        int s = col_src[e];
        float wgt = di * dinv[s];
        z0 += wgt * Y4[2 * s];
        z1 += wgt * Y4[2 * s + 1];
    }
    z0 += b4[0];
    z1 += b4[1];
    float m = fmaxf(z0, z1);
    float l = m + logf(expf(z0 - m) + expf(z1 - m));
    out[2 * i] = z0 - l;
    out[2 * i + 1] = z1 - l;
}

// ---------------- launch ----------------

extern "C" void kernel_launch(void* const* d_in, const int* in_sizes, int n_in,
                              void* d_out, int out_size, void* d_ws, size_t ws_size,
                              hipStream_t stream) {
    const float* x  = (const float*)d_in[0];
    const int*   ei = (const int*)d_in[1];
    const float* W1 = (const float*)d_in[3];
    const float* b1 = (const float*)d_in[4];
    const float* W2 = (const float*)d_in[5];
    const float* b2 = (const float*)d_in[6];
    const float* W3 = (const float*)d_in[7];
    const float* b3 = (const float*)d_in[8];
    const float* W4 = (const float*)d_in[9];
    const float* b4 = (const float*)d_in[10];
    float* out = (float*)d_out;

    char* ws = (char*)d_ws;
    // workspace layout (bytes, 256-aligned)
    float*          dinv    = (float*)(ws + 0);                  // 40,000
    int*            cnt     = (int*)  (ws + 40960);
    int*            row_cnt = (int*)  (ws + 81920);
    int*            row_ptr = (int*)  (ws + 122880);             // 40,004
    int*            col_src = (int*)  (ws + 163840);             // 640,000
    float*          Y4      = (float*)(ws + 803840);             // 80,000
    unsigned short* xb      = (unsigned short*)(ws + 884224);    // MPAD*K1PAD*2 = 45,875,200
    unsigned short* W1t     = (unsigned short*)(ws + 46759424);  // 2,293,760
    unsigned short* W2t     = (unsigned short*)(ws + 49053184);  // 524,288
    unsigned short* W3t     = (unsigned short*)(ws + 49577472);  // 524,288
    unsigned short* Yb      = (unsigned short*)(ws + 50101760);  // MPAD*512*2 = 10,485,760
    unsigned short* Hb      = (unsigned short*)(ws + 60587520);  // 10,485,760
    // total: 71,073,280 bytes
    if (ws_size < 71073280) return;

    // graph preprocessing
    k_init<<<40, 256, 0, stream>>>(cnt, row_cnt, NNODES);
    k_hist<<<625, 256, 0, stream>>>(ei, cnt, NEDGES);
    k_scan<<<1, 1024, 0, stream>>>(cnt, row_ptr, dinv, NNODES);
    k_fill<<<625, 256, 0, stream>>>(ei, row_ptr, row_cnt, col_src, NEDGES);

    // bf16 conversions
    k_cvt_x<<<MPAD, 256, 0, stream>>>(x, xb);
    k_cvt_w<<<dim3(13, HDIM), 256, 0, stream>>>(W1, W2, W3, W1t, W2t, W3t);

    const int ggrid = (MPAD / 128) * 8;   // 640 linear blocks, XCD-grouped decode
    const int agrid = (MPAD * 64) / 256;  // one wave per (padded) node

    // layer 1
    k_gemm_bf16<<<ggrid, 256, 0, stream>>>(xb, W1t, Yb, NNODES, K1PAD);
    k_agg<<<agrid, 256, 0, stream>>>(Yb, dinv, row_ptr, col_src, b1, Hb, 1);
    // layer 2
    k_gemm_bf16<<<ggrid, 256, 0, stream>>>(Hb, W2t, Yb, NNODES, HDIM);
    k_agg<<<agrid, 256, 0, stream>>>(Yb, dinv, row_ptr, col_src, b2, Hb, 1);
    // layer 3
    k_gemm_bf16<<<ggrid, 256, 0, stream>>>(Hb, W3t, Yb, NNODES, HDIM);
    k_agg<<<agrid, 256, 0, stream>>>(Yb, dinv, row_ptr, col_src, b3, Hb, 1);
    // layer 4 + log_softmax
    k_gemm4<<<2500, 256, 0, stream>>>(Hb, W4, Y4, NNODES);
    k_final<<<40, 256, 0, stream>>>(Y4, dinv, row_ptr, col_src, b4, out, NNODES);
}